// Round 12
// baseline (321.416 us; speedup 1.0000x reference)
//
#include <hip/hip_runtime.h>

// Bahdanau attention, MI355X. B=32, S=4096, D=U=512, fp32 in/out.
// R12 = R11 with the B ring-3 clobber fixed: prefetch of B(kg+3) goes AFTER
//   the MFMA cluster (slot (kg+3)%3 == kg%3 is only free once consumed).
// R11: prep_values hoists fp32->bf16 cvt out of the hot loop (valf, 128MB ws,
//   fragment-linear). Score staging = 2 short8 loads + 2 ds_write_b128/thread.
//   Context reads valf fragment-order. Fallback to R6 path if ws too small.
#define NB 32
#define NS 4096
#define ND 512
#define NU 512

typedef __attribute__((ext_vector_type(8))) __bf16 bf16x8;
typedef __attribute__((ext_vector_type(8))) short short8;
typedef __attribute__((ext_vector_type(4))) float f32x4;

union Cvt8 { __bf16 h[8]; short8 s8; };

__device__ __forceinline__ float fast_tanh(float x) {
  float e = __expf(2.0f * x);
  return 1.0f - __fdividef(2.0f, e + 1.0f);
}

// ---- K0a: pack W1 (f32 [D][U]) -> bf16 MFMA B-fragment order ----
// W1f[ks][ct][lane][j]: k = ks*32 + (lane>>4)*8 + j, u = ct*16 + (lane&15)
__global__ void pack_w1_kernel(const float* __restrict__ W1, __bf16* __restrict__ W1f) {
  int idx = blockIdx.x * 256 + threadIdx.x;   // [16 ks][32 ct][64 lane]
  int l  = idx & 63;
  int ct = (idx >> 6) & 31;
  int ks = idx >> 11;
  int col   = ct * 16 + (l & 15);
  int kbase = ks * 32 + (l >> 4) * 8;
  Cvt8 u;
#pragma unroll
  for (int j = 0; j < 8; ++j) u.h[j] = (__bf16)W1[(size_t)(kbase + j) * NU + col];
  *reinterpret_cast<short8*>(W1f + (size_t)idx * 8) = u.s8;
}

// ---- K0b: pq[b][u] = query[b]@W2[:,u] + b2[u] + b1[u] ----
__global__ void proj_query_kernel(const float* __restrict__ query, const float* __restrict__ W2,
                                  const float* __restrict__ b2, const float* __restrict__ b1,
                                  float* __restrict__ pq) {
  int b = blockIdx.y;
  int u = blockIdx.x * 256 + threadIdx.x;
  const float* q = query + (size_t)b * ND;
  float acc = b2[u] + b1[u];
  for (int k = 0; k < ND; ++k) acc += q[k] * W2[(size_t)k * NU + u];
  pq[(size_t)b * NU + u] = acc;
}

// ---- K1: prep values fp32 -> valf bf16 fragment-linear ----
// Chunk C = (b*64+T)*4096 + (tg*16+kg)*64 + ln holds 8 bf16 of
// row s = T*64 + tg*16 + (ln&15), dims k = kg*32 + (ln>>4)*8 + 0..7.
__global__ void prep_values_kernel(const float* __restrict__ values, short8* __restrict__ valf) {
  int blk = blockIdx.x;                       // 2048 = 32 b * 64 tiles
  int tid = threadIdx.x;                      // 512
  size_t base = (size_t)blk * 4096;
  const float* vbase = values + (size_t)blk * 64 * ND;
#pragma unroll
  for (int i = 0; i < 8; ++i) {
    int c  = i * 512 + tid;
    int t  = c >> 10;
    int kg = (c >> 6) & 15;
    int ln = c & 63;
    int s  = t * 16 + (ln & 15);
    int c8 = kg * 4 + (ln >> 4);
    const f32x4* p = reinterpret_cast<const f32x4*>(vbase + (size_t)s * ND + c8 * 8);
    f32x4 f0 = p[0], f1 = p[1];
    Cvt8 u;
    u.h[0] = (__bf16)f0.x; u.h[1] = (__bf16)f0.y; u.h[2] = (__bf16)f0.z; u.h[3] = (__bf16)f0.w;
    u.h[4] = (__bf16)f1.x; u.h[5] = (__bf16)f1.y; u.h[6] = (__bf16)f1.z; u.h[7] = (__bf16)f1.w;
    valf[base + c] = u.s8;
  }
}

// ---- K2 fast: score from valf (bf16 staged, trivial staging) ----
__global__ __launch_bounds__(512, 4)
void score_kernel_bf16(const short8* __restrict__ valf, const __bf16* __restrict__ W1f,
                       const float* __restrict__ pq, const float* __restrict__ V,
                       float* __restrict__ scoreW) {
  __shared__ __align__(16) char ldsb[67584];  // 64KB tile + 2KB reduce buf
  float* sbuf = (float*)(ldsb + 65536);
  short8* lds8 = (short8*)ldsb;

  int bid = blockIdx.x;                       // 2048 = 32 b * 64 tiles
  int b = bid >> 6;
  int s0 = (bid & 63) * 64;
  int tid = threadIdx.x;                      // 512
  int l = tid & 63;
  int w = tid >> 6;
  int lane_col = l & 15;
  int lane_k8  = l >> 4;

  float pqv[4], Vv[4];
#pragma unroll
  for (int nb = 0; nb < 2; ++nb)
#pragma unroll
    for (int cf = 0; cf < 2; ++cf) {
      int col = nb * 256 + w * 32 + cf * 16 + lane_col;
      pqv[nb * 2 + cf] = pq[(size_t)b * NU + col];
      Vv[nb * 2 + cf]  = V[col];
    }

  // stage: 4096 chunks, 8 per thread, pure copy (no cvt)
  const short8* vsrc = valf + (size_t)bid * 4096;
#pragma unroll
  for (int i = 0; i < 8; ++i) {
    int c = i * 512 + tid;
    lds8[c] = vsrc[c];
  }
  __syncthreads();

  float partial[4][4];
#pragma unroll
  for (int t = 0; t < 4; ++t)
#pragma unroll
    for (int r = 0; r < 4; ++r) partial[t][r] = 0.f;

#pragma unroll
  for (int nb = 0; nb < 2; ++nb) {
    f32x4 acc[4][2];
#pragma unroll
    for (int t = 0; t < 4; ++t)
#pragma unroll
      for (int cf = 0; cf < 2; ++cf) acc[t][cf] = (f32x4){0.f, 0.f, 0.f, 0.f};

    const __bf16* wp = W1f + ((size_t)(nb * 16 + w * 2) * 64 + l) * 8;

    bf16x8 aa[2][4];                          // A ring-2 (LDS)
    bf16x8 bbb[3][2];                         // B ring-3 (L2/L3)
#pragma unroll
    for (int t = 0; t < 4; ++t)
      aa[0][t] = *reinterpret_cast<const bf16x8*>(ldsb + (((t * 16 + 0) * 64 + l) << 4));
#pragma unroll
    for (int j = 0; j < 3; ++j)
#pragma unroll
      for (int cf = 0; cf < 2; ++cf)
        bbb[j][cf] = *reinterpret_cast<const bf16x8*>(wp + (size_t)j * 16384 + cf * 512);

#pragma unroll
    for (int kg = 0; kg < 16; ++kg) {
      const int cur = kg & 1, nxt = cur ^ 1;
      if (kg < 15) {
#pragma unroll
        for (int t = 0; t < 4; ++t)
          aa[nxt][t] = *reinterpret_cast<const bf16x8*>(ldsb + (((t * 16 + kg + 1) * 64 + l) << 4));
      }
      // MFMA cluster consumes bbb[kg%3] ...
#pragma unroll
      for (int cf = 0; cf < 2; ++cf)
#pragma unroll
        for (int t = 0; t < 4; ++t)
          acc[t][cf] = __builtin_amdgcn_mfma_f32_16x16x32_bf16(aa[cur][t], bbb[kg % 3][cf], acc[t][cf], 0, 0, 0);
      // ... THEN the freed slot (kg+3)%3 == kg%3 is refilled (R11 bug: was before)
      if (kg < 13) {
#pragma unroll
        for (int cf = 0; cf < 2; ++cf)
          bbb[kg % 3][cf] = *reinterpret_cast<const bf16x8*>(wp + (size_t)(kg + 3) * 16384 + cf * 512);
      }
    }

#pragma unroll
    for (int cf = 0; cf < 2; ++cf)
#pragma unroll
      for (int t = 0; t < 4; ++t)
#pragma unroll
        for (int r = 0; r < 4; ++r)
          partial[t][r] += fast_tanh(acc[t][cf][r] + pqv[nb * 2 + cf]) * Vv[nb * 2 + cf];
  }

#pragma unroll
  for (int off = 1; off < 16; off <<= 1)
#pragma unroll
    for (int t = 0; t < 4; ++t)
#pragma unroll
      for (int r = 0; r < 4; ++r) partial[t][r] += __shfl_xor(partial[t][r], off);

  if (lane_col == 0) {
#pragma unroll
    for (int t = 0; t < 4; ++t)
#pragma unroll
      for (int r = 0; r < 4; ++r)
        sbuf[w * 64 + t * 16 + lane_k8 * 4 + r] = partial[t][r];
  }
  __syncthreads();
  if (tid < 64) {
    float sc = 0.f;
#pragma unroll
    for (int wv = 0; wv < 8; ++wv) sc += sbuf[wv * 64 + tid];
    scoreW[(size_t)b * NS + s0 + tid] = sc;   // bv omitted: softmax shift-invariant
  }
}

// ---- K2 fallback: R6 score (fp32 staging + cvt in-kernel) ----
__global__ __launch_bounds__(512, 4)
void score_kernel_f32(const float* __restrict__ values, const __bf16* __restrict__ W1f,
                      const float* __restrict__ pq, const float* __restrict__ V,
                      float* __restrict__ scoreW) {
  __shared__ __align__(16) char ldsb[67584];
  float* sbuf = (float*)(ldsb + 65536);
  int bid = blockIdx.x;
  int b = bid >> 6;
  int s0 = (bid & 63) * 64;
  int tid = threadIdx.x;
  int l = tid & 63;
  int w = tid >> 6;
  int lane_col = l & 15;
  int lane_k8  = l >> 4;
  float pqv[4], Vv[4];
#pragma unroll
  for (int nb = 0; nb < 2; ++nb)
#pragma unroll
    for (int cf = 0; cf < 2; ++cf) {
      int col = nb * 256 + w * 32 + cf * 16 + lane_col;
      pqv[nb * 2 + cf] = pq[(size_t)b * NU + col];
      Vv[nb * 2 + cf]  = V[col];
    }
  const float* vbase = values + ((size_t)b * NS + s0) * ND;
#pragma unroll
  for (int i = 0; i < 8; ++i) {
    int c  = i * 512 + tid;
    int t  = c >> 10;
    int kg = (c >> 6) & 15;
    int ln = c & 63;
    int s  = t * 16 + (ln & 15);
    int c8 = kg * 4 + (ln >> 4);
    const f32x4* p = reinterpret_cast<const f32x4*>(vbase + (size_t)s * ND + c8 * 8);
    f32x4 f0 = p[0], f1 = p[1];
    Cvt8 u;
    u.h[0] = (__bf16)f0.x; u.h[1] = (__bf16)f0.y; u.h[2] = (__bf16)f0.z; u.h[3] = (__bf16)f0.w;
    u.h[4] = (__bf16)f1.x; u.h[5] = (__bf16)f1.y; u.h[6] = (__bf16)f1.z; u.h[7] = (__bf16)f1.w;
    *reinterpret_cast<short8*>(ldsb + (size_t)c * 16) = u.s8;
  }
  __syncthreads();
  float partial[4][4];
#pragma unroll
  for (int t = 0; t < 4; ++t)
#pragma unroll
    for (int r = 0; r < 4; ++r) partial[t][r] = 0.f;
#pragma unroll
  for (int nb = 0; nb < 2; ++nb) {
    f32x4 acc[4][2];
#pragma unroll
    for (int t = 0; t < 4; ++t)
#pragma unroll
      for (int cf = 0; cf < 2; ++cf) acc[t][cf] = (f32x4){0.f, 0.f, 0.f, 0.f};
    const __bf16* wp = W1f + ((size_t)(nb * 16 + w * 2) * 64 + l) * 8;
    bf16x8 aa[2][4];
    bf16x8 bbb[2][2];
#pragma unroll
    for (int t = 0; t < 4; ++t)
      aa[0][t] = *reinterpret_cast<const bf16x8*>(ldsb + (((t * 16 + 0) * 64 + l) << 4));
#pragma unroll
    for (int cf = 0; cf < 2; ++cf)
      bbb[0][cf] = *reinterpret_cast<const bf16x8*>(wp + (size_t)0 * 16384 + cf * 512);
#pragma unroll
    for (int kg = 0; kg < 16; ++kg) {
      const int cur = kg & 1, nxt = cur ^ 1;
      if (kg < 15) {
#pragma unroll
        for (int cf = 0; cf < 2; ++cf)
          bbb[nxt][cf] = *reinterpret_cast<const bf16x8*>(wp + (size_t)(kg + 1) * 16384 + cf * 512);
#pragma unroll
        for (int t = 0; t < 4; ++t)
          aa[nxt][t] = *reinterpret_cast<const bf16x8*>(ldsb + (((t * 16 + kg + 1) * 64 + l) << 4));
      }
#pragma unroll
      for (int cf = 0; cf < 2; ++cf)
#pragma unroll
        for (int t = 0; t < 4; ++t)
          acc[t][cf] = __builtin_amdgcn_mfma_f32_16x16x32_bf16(aa[cur][t], bbb[cur][cf], acc[t][cf], 0, 0, 0);
    }
#pragma unroll
    for (int cf = 0; cf < 2; ++cf)
#pragma unroll
      for (int t = 0; t < 4; ++t)
#pragma unroll
        for (int r = 0; r < 4; ++r)
          partial[t][r] += fast_tanh(acc[t][cf][r] + pqv[nb * 2 + cf]) * Vv[nb * 2 + cf];
  }
#pragma unroll
  for (int off = 1; off < 16; off <<= 1)
#pragma unroll
    for (int t = 0; t < 4; ++t)
#pragma unroll
      for (int r = 0; r < 4; ++r) partial[t][r] += __shfl_xor(partial[t][r], off);
  if (lane_col == 0) {
#pragma unroll
    for (int t = 0; t < 4; ++t)
#pragma unroll
      for (int r = 0; r < 4; ++r)
        sbuf[w * 64 + t * 16 + lane_k8 * 4 + r] = partial[t][r];
  }
  __syncthreads();
  if (tid < 64) {
    float sc = 0.f;
#pragma unroll
    for (int wv = 0; wv < 8; ++wv) sc += sbuf[wv * 64 + tid];
    scoreW[(size_t)b * NS + s0 + tid] = sc;
  }
}

// ---- K3: softmax over S per batch -> attention weights (d_out tail) ----
__global__ void softmax_kernel(const float* __restrict__ scoreW, float* __restrict__ attn) {
  int b = blockIdx.x, tid = threadIdx.x;      // 256 threads
  __shared__ float sred[8];
  const float* sc = scoreW + (size_t)b * NS;
  float m = -3.0e38f;
  for (int s = tid; s < NS; s += 256) m = fmaxf(m, sc[s]);
#pragma unroll
  for (int off = 1; off < 64; off <<= 1) m = fmaxf(m, __shfl_xor(m, off));
  if ((tid & 63) == 0) sred[tid >> 6] = m;
  __syncthreads();
  m = fmaxf(fmaxf(sred[0], sred[1]), fmaxf(sred[2], sred[3]));
  float sum = 0.f;
  for (int s = tid; s < NS; s += 256) sum += __expf(sc[s] - m);
#pragma unroll
  for (int off = 1; off < 64; off <<= 1) sum += __shfl_xor(sum, off);
  if ((tid & 63) == 0) sred[4 + (tid >> 6)] = sum;
  __syncthreads();
  float inv = 1.f / (sred[4] + sred[5] + sred[6] + sred[7]);
  float* ab = attn + (size_t)b * NS;
  for (int s = tid; s < NS; s += 256) ab[s] = __expf(sc[s] - m) * inv;
}

// ---- K4 fast: context from valf fragment layout ----
// Block (b,kg): 256 threads = 4 waves; wave w = row-group tg. Lane ln owns
// dims d = kg*32 + (ln>>4)*8 + j for rows s = T*64 + w*16 + (ln&15), T=0..63.
__global__ void context_valf_kernel(const short8* __restrict__ valf,
                                    const float* __restrict__ attn,
                                    float* __restrict__ ctx) {
  __shared__ float sbuf[128];                 // [4 waves][32 dims]
  int blk = blockIdx.x;                       // 512 = 32 b * 16 kg
  int b = blk >> 4, kg = blk & 15;
  int tid = threadIdx.x;                      // 256
  int w = tid >> 6, ln = tid & 63;
  const float* ab = attn + (size_t)b * NS;

  float acc[8];
#pragma unroll
  for (int j = 0; j < 8; ++j) acc[j] = 0.f;

  for (int T = 0; T < 64; ++T) {
    size_t C = ((size_t)(b * 64 + T)) * 4096 + (size_t)(w * 16 + kg) * 64 + ln;
    short8 v = valf[C];
    float wv = ab[T * 64 + w * 16 + (ln & 15)];
    Cvt8 u; u.s8 = v;
#pragma unroll
    for (int j = 0; j < 8; ++j) acc[j] += wv * (float)u.h[j];
  }
  // reduce over the 16 lanes sharing ln>>4 (same dims, different rows)
#pragma unroll
  for (int off = 1; off < 16; off <<= 1)
#pragma unroll
    for (int j = 0; j < 8; ++j) acc[j] += __shfl_xor(acc[j], off);
  if ((ln & 15) == 0) {
#pragma unroll
    for (int j = 0; j < 8; ++j) sbuf[w * 32 + (ln >> 4) * 8 + j] = acc[j];
  }
  __syncthreads();
  if (tid < 32) {
    float s = sbuf[tid] + sbuf[32 + tid] + sbuf[64 + tid] + sbuf[96 + tid];
    ctx[(size_t)b * ND + kg * 32 + tid] = s;
  }
}

// ---- K4/K5 fallback: context from fp32 values ----
__global__ void context_partial_kernel(const float* __restrict__ values,
                                       const float* __restrict__ attn,
                                       float* __restrict__ ctxpart) {
  int blk = blockIdx.x;
  int b = blk >> 4, c = blk & 15;
  int tid = threadIdx.x;
  int t2 = tid & 127;
  int sg = tid >> 7;
  const float* vb = values + ((size_t)b * NS + c * 256) * ND;
  const float* ab = attn + (size_t)b * NS + c * 256;
  f32x4 acc = {0.f, 0.f, 0.f, 0.f};
  for (int s = sg; s < 256; s += 2) {
    float wv = ab[s];
    f32x4 v = *reinterpret_cast<const f32x4*>(vb + (size_t)s * ND + t2 * 4);
    acc += v * wv;
  }
  __shared__ f32x4 red[128];
  if (sg == 1) red[t2] = acc;
  __syncthreads();
  if (sg == 0) {
    acc += red[t2];
    *reinterpret_cast<f32x4*>(ctxpart + (size_t)blk * ND + t2 * 4) = acc;
  }
}
__global__ void context_reduce_kernel(const float* __restrict__ ctxpart, float* __restrict__ ctx) {
  int b = blockIdx.x, tid = threadIdx.x;
  f32x4 acc = {0.f, 0.f, 0.f, 0.f};
  for (int c = 0; c < 16; ++c)
    acc += *reinterpret_cast<const f32x4*>(ctxpart + (size_t)(b * 16 + c) * ND + tid * 4);
  *reinterpret_cast<f32x4*>(ctx + (size_t)b * ND + tid * 4) = acc;
}

extern "C" void kernel_launch(void* const* d_in, const int* in_sizes, int n_in,
                              void* d_out, int out_size, void* d_ws, size_t ws_size,
                              hipStream_t stream) {
  const float* query  = (const float*)d_in[0];
  const float* values = (const float*)d_in[1];
  const float* W1     = (const float*)d_in[2];
  const float* b1     = (const float*)d_in[3];
  const float* W2     = (const float*)d_in[4];
  const float* b2     = (const float*)d_in[5];
  const float* V      = (const float*)d_in[6];
  // d_in[7] = bv: softmax-invariant, score not an output: dropped.

  float* ctx_out  = (float*)d_out;            // [32][512]
  float* attn_out = ctx_out + NB * ND;        // [32][4096]

  char* ws = (char*)d_ws;
  __bf16* W1f    = (__bf16*)ws;               // 512 KB
  float*  pq     = (float*)(ws + 524288);     // 64 KB
  float*  scoreW = (float*)(ws + 589824);     // 512 KB
  float*  ctxp   = (float*)(ws + 1114112);    // 1 MB (fallback only)
  short8* valf   = (short8*)(ws + 2162688);   // 128 MB (fast path)
  const size_t need = 2162688 + (size_t)NB * NS * ND * 2;

  hipLaunchKernelGGL(pack_w1_kernel,    dim3(128),   dim3(256), 0, stream, W1, W1f);
  hipLaunchKernelGGL(proj_query_kernel, dim3(2, NB), dim3(256), 0, stream, query, W2, b2, b1, pq);

  if (ws_size >= need) {
    hipLaunchKernelGGL(prep_values_kernel, dim3(2048), dim3(512), 0, stream, values, valf);
    hipLaunchKernelGGL(score_kernel_bf16,  dim3(2048), dim3(512), 0, stream, valf, W1f, pq, V, scoreW);
    hipLaunchKernelGGL(softmax_kernel,     dim3(NB),   dim3(256), 0, stream, scoreW, attn_out);
    hipLaunchKernelGGL(context_valf_kernel,dim3(NB*16),dim3(256), 0, stream, valf, attn_out, ctx_out);
  } else {
    hipLaunchKernelGGL(score_kernel_f32,   dim3(2048), dim3(512), 0, stream, values, W1f, pq, V, scoreW);
    hipLaunchKernelGGL(softmax_kernel,     dim3(NB),   dim3(256), 0, stream, scoreW, attn_out);
    hipLaunchKernelGGL(context_partial_kernel, dim3(NB*16), dim3(256), 0, stream, values, attn_out, ctxp);
    hipLaunchKernelGGL(context_reduce_kernel,  dim3(NB),    dim3(128), 0, stream, ctxp, ctx_out);
  }
}

// Round 13
// 288.144 us; speedup vs baseline: 1.1155x; 1.1155x over previous
//
#include <hip/hip_runtime.h>

// Bahdanau attention, MI355X. B=32, S=4096, D=U=512, fp32 in/out.
// R13 = R12 with (a) B prefetch back to ring-2 (ring-3 spilled AGAIN: 332MB
//   scratch writes; this shape's hard budget = ring-2 A + ring-2 B, R6-proven),
//   (b) score staging via __builtin_amdgcn_global_load_lds width=16 (staging
//   is now a pure linear copy; LDS dest = wave-uniform base + lane*16 exactly
//   matches the HW pattern; zero staging VGPRs, zero ds_writes, 8 loads in
//   flight; __syncthreads drains vmcnt).
// R11/12: prep_values hoists fp32->bf16 cvt (valf, 128MB ws, fragment-linear);
//   context reads valf. Fallback to R6 path if ws too small.
#define NB 32
#define NS 4096
#define ND 512
#define NU 512

typedef __attribute__((ext_vector_type(8))) __bf16 bf16x8;
typedef __attribute__((ext_vector_type(8))) short short8;
typedef __attribute__((ext_vector_type(4))) float f32x4;

union Cvt8 { __bf16 h[8]; short8 s8; };

__device__ __forceinline__ float fast_tanh(float x) {
  float e = __expf(2.0f * x);
  return 1.0f - __fdividef(2.0f, e + 1.0f);
}

__device__ __forceinline__ void gload_lds16(const void* g, void* l) {
  __builtin_amdgcn_global_load_lds(
      (const __attribute__((address_space(1))) unsigned int*)g,
      (__attribute__((address_space(3))) unsigned int*)l, 16, 0, 0);
}

// ---- K0a: pack W1 (f32 [D][U]) -> bf16 MFMA B-fragment order ----
// W1f[ks][ct][lane][j]: k = ks*32 + (lane>>4)*8 + j, u = ct*16 + (lane&15)
__global__ void pack_w1_kernel(const float* __restrict__ W1, __bf16* __restrict__ W1f) {
  int idx = blockIdx.x * 256 + threadIdx.x;   // [16 ks][32 ct][64 lane]
  int l  = idx & 63;
  int ct = (idx >> 6) & 31;
  int ks = idx >> 11;
  int col   = ct * 16 + (l & 15);
  int kbase = ks * 32 + (l >> 4) * 8;
  Cvt8 u;
#pragma unroll
  for (int j = 0; j < 8; ++j) u.h[j] = (__bf16)W1[(size_t)(kbase + j) * NU + col];
  *reinterpret_cast<short8*>(W1f + (size_t)idx * 8) = u.s8;
}

// ---- K0b: pq[b][u] = query[b]@W2[:,u] + b2[u] + b1[u] ----
__global__ void proj_query_kernel(const float* __restrict__ query, const float* __restrict__ W2,
                                  const float* __restrict__ b2, const float* __restrict__ b1,
                                  float* __restrict__ pq) {
  int b = blockIdx.y;
  int u = blockIdx.x * 256 + threadIdx.x;
  const float* q = query + (size_t)b * ND;
  float acc = b2[u] + b1[u];
  for (int k = 0; k < ND; ++k) acc += q[k] * W2[(size_t)k * NU + u];
  pq[(size_t)b * NU + u] = acc;
}

// ---- K1: prep values fp32 -> valf bf16 fragment-linear ----
// Chunk C = blk*4096 + (t*16+kg)*64 + ln holds 8 bf16 of row s = t*16+(ln&15),
// dims k = kg*32 + (ln>>4)*8 + 0..7 of 64-row tile blk.
__global__ void prep_values_kernel(const float* __restrict__ values, short8* __restrict__ valf) {
  int blk = blockIdx.x;                       // 2048 = 32 b * 64 tiles
  int tid = threadIdx.x;                      // 512
  size_t base = (size_t)blk * 4096;
  const float* vbase = values + (size_t)blk * 64 * ND;
#pragma unroll
  for (int i = 0; i < 8; ++i) {
    int c  = i * 512 + tid;
    int t  = c >> 10;
    int kg = (c >> 6) & 15;
    int ln = c & 63;
    int s  = t * 16 + (ln & 15);
    int c8 = kg * 4 + (ln >> 4);
    const f32x4* p = reinterpret_cast<const f32x4*>(vbase + (size_t)s * ND + c8 * 8);
    f32x4 f0 = p[0], f1 = p[1];
    Cvt8 u;
    u.h[0] = (__bf16)f0.x; u.h[1] = (__bf16)f0.y; u.h[2] = (__bf16)f0.z; u.h[3] = (__bf16)f0.w;
    u.h[4] = (__bf16)f1.x; u.h[5] = (__bf16)f1.y; u.h[6] = (__bf16)f1.z; u.h[7] = (__bf16)f1.w;
    valf[base + c] = u.s8;
  }
}

// ---- K2 fast: score from valf (global_load_lds staging, ring-2 prefetch) ----
__global__ __launch_bounds__(512, 4)
void score_kernel_bf16(const short8* __restrict__ valf, const __bf16* __restrict__ W1f,
                       const float* __restrict__ pq, const float* __restrict__ V,
                       float* __restrict__ scoreW) {
  __shared__ __align__(16) char ldsb[67584];  // 64KB tile + 2KB reduce buf
  float* sbuf = (float*)(ldsb + 65536);

  int bid = blockIdx.x;                       // 2048 = 32 b * 64 tiles
  int b = bid >> 6;
  int s0 = (bid & 63) * 64;
  int tid = threadIdx.x;                      // 512
  int l = tid & 63;
  int w = tid >> 6;
  int lane_col = l & 15;
  int lane_k8  = l >> 4;

  float pqv[4], Vv[4];
#pragma unroll
  for (int nb = 0; nb < 2; ++nb)
#pragma unroll
    for (int cf = 0; cf < 2; ++cf) {
      int col = nb * 256 + w * 32 + cf * 16 + lane_col;
      pqv[nb * 2 + cf] = pq[(size_t)b * NU + col];
      Vv[nb * 2 + cf]  = V[col];
    }

  // stage: 8 x global_load_lds_dwordx4 per thread (linear both sides, no regs)
  const short8* vsrc = valf + (size_t)bid * 4096;
#pragma unroll
  for (int i = 0; i < 8; ++i) {
    int c = i * 512 + tid;
    gload_lds16(vsrc + c, ldsb + (size_t)c * 16);
  }
  __syncthreads();                            // compiler drains vmcnt here

  float partial[4][4];
#pragma unroll
  for (int t = 0; t < 4; ++t)
#pragma unroll
    for (int r = 0; r < 4; ++r) partial[t][r] = 0.f;

#pragma unroll
  for (int nb = 0; nb < 2; ++nb) {
    f32x4 acc[4][2];
#pragma unroll
    for (int t = 0; t < 4; ++t)
#pragma unroll
      for (int cf = 0; cf < 2; ++cf) acc[t][cf] = (f32x4){0.f, 0.f, 0.f, 0.f};

    const __bf16* wp = W1f + ((size_t)(nb * 16 + w * 2) * 64 + l) * 8;

    bf16x8 aa[2][4];                          // A ring-2 (LDS)
    bf16x8 bbb[2][2];                         // B ring-2 (L2/L3) -- hard budget
#pragma unroll
    for (int t = 0; t < 4; ++t)
      aa[0][t] = *reinterpret_cast<const bf16x8*>(ldsb + (((t * 16 + 0) * 64 + l) << 4));
#pragma unroll
    for (int cf = 0; cf < 2; ++cf)
      bbb[0][cf] = *reinterpret_cast<const bf16x8*>(wp + (size_t)0 * 16384 + cf * 512);

#pragma unroll
    for (int kg = 0; kg < 16; ++kg) {
      const int cur = kg & 1, nxt = cur ^ 1;
      if (kg < 15) {
#pragma unroll
        for (int cf = 0; cf < 2; ++cf)     // B first: longest latency
          bbb[nxt][cf] = *reinterpret_cast<const bf16x8*>(wp + (size_t)(kg + 1) * 16384 + cf * 512);
#pragma unroll
        for (int t = 0; t < 4; ++t)
          aa[nxt][t] = *reinterpret_cast<const bf16x8*>(ldsb + (((t * 16 + kg + 1) * 64 + l) << 4));
      }
#pragma unroll
      for (int cf = 0; cf < 2; ++cf)
#pragma unroll
        for (int t = 0; t < 4; ++t)
          acc[t][cf] = __builtin_amdgcn_mfma_f32_16x16x32_bf16(aa[cur][t], bbb[cur][cf], acc[t][cf], 0, 0, 0);
    }

#pragma unroll
    for (int cf = 0; cf < 2; ++cf)
#pragma unroll
      for (int t = 0; t < 4; ++t)
#pragma unroll
        for (int r = 0; r < 4; ++r)
          partial[t][r] += fast_tanh(acc[t][cf][r] + pqv[nb * 2 + cf]) * Vv[nb * 2 + cf];
  }

#pragma unroll
  for (int off = 1; off < 16; off <<= 1)
#pragma unroll
    for (int t = 0; t < 4; ++t)
#pragma unroll
      for (int r = 0; r < 4; ++r) partial[t][r] += __shfl_xor(partial[t][r], off);

  if (lane_col == 0) {
#pragma unroll
    for (int t = 0; t < 4; ++t)
#pragma unroll
      for (int r = 0; r < 4; ++r)
        sbuf[w * 64 + t * 16 + lane_k8 * 4 + r] = partial[t][r];
  }
  __syncthreads();
  if (tid < 64) {
    float sc = 0.f;
#pragma unroll
    for (int wv = 0; wv < 8; ++wv) sc += sbuf[wv * 64 + tid];
    scoreW[(size_t)b * NS + s0 + tid] = sc;   // bv omitted: softmax shift-invariant
  }
}

// ---- K2 fallback: R6 score (fp32 staging + cvt in-kernel) ----
__global__ __launch_bounds__(512, 4)
void score_kernel_f32(const float* __restrict__ values, const __bf16* __restrict__ W1f,
                      const float* __restrict__ pq, const float* __restrict__ V,
                      float* __restrict__ scoreW) {
  __shared__ __align__(16) char ldsb[67584];
  float* sbuf = (float*)(ldsb + 65536);
  int bid = blockIdx.x;
  int b = bid >> 6;
  int s0 = (bid & 63) * 64;
  int tid = threadIdx.x;
  int l = tid & 63;
  int w = tid >> 6;
  int lane_col = l & 15;
  int lane_k8  = l >> 4;
  float pqv[4], Vv[4];
#pragma unroll
  for (int nb = 0; nb < 2; ++nb)
#pragma unroll
    for (int cf = 0; cf < 2; ++cf) {
      int col = nb * 256 + w * 32 + cf * 16 + lane_col;
      pqv[nb * 2 + cf] = pq[(size_t)b * NU + col];
      Vv[nb * 2 + cf]  = V[col];
    }
  const float* vbase = values + ((size_t)b * NS + s0) * ND;
#pragma unroll
  for (int i = 0; i < 8; ++i) {
    int c  = i * 512 + tid;
    int t  = c >> 10;
    int kg = (c >> 6) & 15;
    int ln = c & 63;
    int s  = t * 16 + (ln & 15);
    int c8 = kg * 4 + (ln >> 4);
    const f32x4* p = reinterpret_cast<const f32x4*>(vbase + (size_t)s * ND + c8 * 8);
    f32x4 f0 = p[0], f1 = p[1];
    Cvt8 u;
    u.h[0] = (__bf16)f0.x; u.h[1] = (__bf16)f0.y; u.h[2] = (__bf16)f0.z; u.h[3] = (__bf16)f0.w;
    u.h[4] = (__bf16)f1.x; u.h[5] = (__bf16)f1.y; u.h[6] = (__bf16)f1.z; u.h[7] = (__bf16)f1.w;
    *reinterpret_cast<short8*>(ldsb + (size_t)c * 16) = u.s8;
  }
  __syncthreads();
  float partial[4][4];
#pragma unroll
  for (int t = 0; t < 4; ++t)
#pragma unroll
    for (int r = 0; r < 4; ++r) partial[t][r] = 0.f;
#pragma unroll
  for (int nb = 0; nb < 2; ++nb) {
    f32x4 acc[4][2];
#pragma unroll
    for (int t = 0; t < 4; ++t)
#pragma unroll
      for (int cf = 0; cf < 2; ++cf) acc[t][cf] = (f32x4){0.f, 0.f, 0.f, 0.f};
    const __bf16* wp = W1f + ((size_t)(nb * 16 + w * 2) * 64 + l) * 8;
    bf16x8 aa[2][4];
    bf16x8 bbb[2][2];
#pragma unroll
    for (int t = 0; t < 4; ++t)
      aa[0][t] = *reinterpret_cast<const bf16x8*>(ldsb + (((t * 16 + 0) * 64 + l) << 4));
#pragma unroll
    for (int cf = 0; cf < 2; ++cf)
      bbb[0][cf] = *reinterpret_cast<const bf16x8*>(wp + (size_t)0 * 16384 + cf * 512);
#pragma unroll
    for (int kg = 0; kg < 16; ++kg) {
      const int cur = kg & 1, nxt = cur ^ 1;
      if (kg < 15) {
#pragma unroll
        for (int cf = 0; cf < 2; ++cf)
          bbb[nxt][cf] = *reinterpret_cast<const bf16x8*>(wp + (size_t)(kg + 1) * 16384 + cf * 512);
#pragma unroll
        for (int t = 0; t < 4; ++t)
          aa[nxt][t] = *reinterpret_cast<const bf16x8*>(ldsb + (((t * 16 + kg + 1) * 64 + l) << 4));
      }
#pragma unroll
      for (int cf = 0; cf < 2; ++cf)
#pragma unroll
        for (int t = 0; t < 4; ++t)
          acc[t][cf] = __builtin_amdgcn_mfma_f32_16x16x32_bf16(aa[cur][t], bbb[cur][cf], acc[t][cf], 0, 0, 0);
    }
#pragma unroll
    for (int cf = 0; cf < 2; ++cf)
#pragma unroll
      for (int t = 0; t < 4; ++t)
#pragma unroll
        for (int r = 0; r < 4; ++r)
          partial[t][r] += fast_tanh(acc[t][cf][r] + pqv[nb * 2 + cf]) * Vv[nb * 2 + cf];
  }
#pragma unroll
  for (int off = 1; off < 16; off <<= 1)
#pragma unroll
    for (int t = 0; t < 4; ++t)
#pragma unroll
      for (int r = 0; r < 4; ++r) partial[t][r] += __shfl_xor(partial[t][r], off);
  if (lane_col == 0) {
#pragma unroll
    for (int t = 0; t < 4; ++t)
#pragma unroll
      for (int r = 0; r < 4; ++r)
        sbuf[w * 64 + t * 16 + lane_k8 * 4 + r] = partial[t][r];
  }
  __syncthreads();
  if (tid < 64) {
    float sc = 0.f;
#pragma unroll
    for (int wv = 0; wv < 8; ++wv) sc += sbuf[wv * 64 + tid];
    scoreW[(size_t)b * NS + s0 + tid] = sc;
  }
}

// ---- K3: softmax over S per batch -> attention weights (d_out tail) ----
__global__ void softmax_kernel(const float* __restrict__ scoreW, float* __restrict__ attn) {
  int b = blockIdx.x, tid = threadIdx.x;      // 256 threads
  __shared__ float sred[8];
  const float* sc = scoreW + (size_t)b * NS;
  float m = -3.0e38f;
  for (int s = tid; s < NS; s += 256) m = fmaxf(m, sc[s]);
#pragma unroll
  for (int off = 1; off < 64; off <<= 1) m = fmaxf(m, __shfl_xor(m, off));
  if ((tid & 63) == 0) sred[tid >> 6] = m;
  __syncthreads();
  m = fmaxf(fmaxf(sred[0], sred[1]), fmaxf(sred[2], sred[3]));
  float sum = 0.f;
  for (int s = tid; s < NS; s += 256) sum += __expf(sc[s] - m);
#pragma unroll
  for (int off = 1; off < 64; off <<= 1) sum += __shfl_xor(sum, off);
  if ((tid & 63) == 0) sred[4 + (tid >> 6)] = sum;
  __syncthreads();
  float inv = 1.f / (sred[4] + sred[5] + sred[6] + sred[7]);
  float* ab = attn + (size_t)b * NS;
  for (int s = tid; s < NS; s += 256) ab[s] = __expf(sc[s] - m) * inv;
}

// ---- K4 fast: context from valf fragment layout ----
// Block (b,kg): 256 threads = 4 waves; wave w = row-group tg. Lane ln owns
// dims d = kg*32 + (ln>>4)*8 + j for rows s = T*64 + w*16 + (ln&15), T=0..63.
__global__ void context_valf_kernel(const short8* __restrict__ valf,
                                    const float* __restrict__ attn,
                                    float* __restrict__ ctx) {
  __shared__ float sbuf[128];                 // [4 waves][32 dims]
  int blk = blockIdx.x;                       // 512 = 32 b * 16 kg
  int b = blk >> 4, kg = blk & 15;
  int tid = threadIdx.x;                      // 256
  int w = tid >> 6, ln = tid & 63;
  const float* ab = attn + (size_t)b * NS;

  float acc[8];
#pragma unroll
  for (int j = 0; j < 8; ++j) acc[j] = 0.f;

  for (int T = 0; T < 64; ++T) {
    size_t C = ((size_t)(b * 64 + T)) * 4096 + (size_t)(w * 16 + kg) * 64 + ln;
    short8 v = valf[C];
    float wv = ab[T * 64 + w * 16 + (ln & 15)];
    Cvt8 u; u.s8 = v;
#pragma unroll
    for (int j = 0; j < 8; ++j) acc[j] += wv * (float)u.h[j];
  }
  // reduce over the 16 lanes sharing ln>>4 (same dims, different rows)
#pragma unroll
  for (int off = 1; off < 16; off <<= 1)
#pragma unroll
    for (int j = 0; j < 8; ++j) acc[j] += __shfl_xor(acc[j], off);
  if ((ln & 15) == 0) {
#pragma unroll
    for (int j = 0; j < 8; ++j) sbuf[w * 32 + (ln >> 4) * 8 + j] = acc[j];
  }
  __syncthreads();
  if (tid < 32) {
    float s = sbuf[tid] + sbuf[32 + tid] + sbuf[64 + tid] + sbuf[96 + tid];
    ctx[(size_t)b * ND + kg * 32 + tid] = s;
  }
}

// ---- K4/K5 fallback: context from fp32 values ----
__global__ void context_partial_kernel(const float* __restrict__ values,
                                       const float* __restrict__ attn,
                                       float* __restrict__ ctxpart) {
  int blk = blockIdx.x;
  int b = blk >> 4, c = blk & 15;
  int tid = threadIdx.x;
  int t2 = tid & 127;
  int sg = tid >> 7;
  const float* vb = values + ((size_t)b * NS + c * 256) * ND;
  const float* ab = attn + (size_t)b * NS + c * 256;
  f32x4 acc = {0.f, 0.f, 0.f, 0.f};
  for (int s = sg; s < 256; s += 2) {
    float wv = ab[s];
    f32x4 v = *reinterpret_cast<const f32x4*>(vb + (size_t)s * ND + t2 * 4);
    acc += v * wv;
  }
  __shared__ f32x4 red[128];
  if (sg == 1) red[t2] = acc;
  __syncthreads();
  if (sg == 0) {
    acc += red[t2];
    *reinterpret_cast<f32x4*>(ctxpart + (size_t)blk * ND + t2 * 4) = acc;
  }
}
__global__ void context_reduce_kernel(const float* __restrict__ ctxpart, float* __restrict__ ctx) {
  int b = blockIdx.x, tid = threadIdx.x;
  f32x4 acc = {0.f, 0.f, 0.f, 0.f};
  for (int c = 0; c < 16; ++c)
    acc += *reinterpret_cast<const f32x4*>(ctxpart + (size_t)(b * 16 + c) * ND + tid * 4);
  *reinterpret_cast<f32x4*>(ctx + (size_t)b * ND + tid * 4) = acc;
}

extern "C" void kernel_launch(void* const* d_in, const int* in_sizes, int n_in,
                              void* d_out, int out_size, void* d_ws, size_t ws_size,
                              hipStream_t stream) {
  const float* query  = (const float*)d_in[0];
  const float* values = (const float*)d_in[1];
  const float* W1     = (const float*)d_in[2];
  const float* b1     = (const float*)d_in[3];
  const float* W2     = (const float*)d_in[4];
  const float* b2     = (const float*)d_in[5];
  const float* V      = (const float*)d_in[6];
  // d_in[7] = bv: softmax-invariant, score not an output: dropped.

  float* ctx_out  = (float*)d_out;            // [32][512]
  float* attn_out = ctx_out + NB * ND;        // [32][4096]

  char* ws = (char*)d_ws;
  __bf16* W1f    = (__bf16*)ws;               // 512 KB
  float*  pq     = (float*)(ws + 524288);     // 64 KB
  float*  scoreW = (float*)(ws + 589824);     // 512 KB
  float*  ctxp   = (float*)(ws + 1114112);    // 1 MB (fallback only)
  short8* valf   = (short8*)(ws + 2162688);   // 128 MB (fast path)
  const size_t need = 2162688 + (size_t)NB * NS * ND * 2;

  hipLaunchKernelGGL(pack_w1_kernel,    dim3(128),   dim3(256), 0, stream, W1, W1f);
  hipLaunchKernelGGL(proj_query_kernel, dim3(2, NB), dim3(256), 0, stream, query, W2, b2, b1, pq);

  if (ws_size >= need) {
    hipLaunchKernelGGL(prep_values_kernel, dim3(2048), dim3(512), 0, stream, values, valf);
    hipLaunchKernelGGL(score_kernel_bf16,  dim3(2048), dim3(512), 0, stream, valf, W1f, pq, V, scoreW);
    hipLaunchKernelGGL(softmax_kernel,     dim3(NB),   dim3(256), 0, stream, scoreW, attn_out);
    hipLaunchKernelGGL(context_valf_kernel,dim3(NB*16),dim3(256), 0, stream, valf, attn_out, ctx_out);
  } else {
    hipLaunchKernelGGL(score_kernel_f32,   dim3(2048), dim3(512), 0, stream, values, W1f, pq, V, scoreW);
    hipLaunchKernelGGL(softmax_kernel,     dim3(NB),   dim3(256), 0, stream, scoreW, attn_out);
    hipLaunchKernelGGL(context_partial_kernel, dim3(NB*16), dim3(256), 0, stream, values, attn_out, ctxp);
    hipLaunchKernelGGL(context_reduce_kernel,  dim3(NB),    dim3(128), 0, stream, ctxp, ctx_out);
  }
}

// Round 14
// 223.617 us; speedup vs baseline: 1.4374x; 1.2886x over previous
//
#include <hip/hip_runtime.h>

// Bahdanau attention, MI355X. B=32, S=4096, D=U=512, fp32 in/out.
// R14: B-panel via shared 4-slot LDS ring + counted vmcnt (T3/T4 adapted).
//   Per iter: s_waitcnt vmcnt(4) [own stage-kg landed; 2 stages in flight,
//   never 0] -> raw s_barrier [all waves' stages landed; restage-safety] ->
//   ds_read A(values LDS)+B(ring slot) -> 8 MFMA -> global_load_lds stage
//   of slice kg+3 (zero VGPRs). B latency now spans 3 iters of compute.
//   LDS 130KB (values 64 + ring 4x16 + sbuf), 1 block/CU, 8 waves, ~100 regs.
//   valf detour dropped (R13: prep+context_valf cost > staging gain).
#define NB 32
#define NS 4096
#define ND 512
#define NU 512

typedef __attribute__((ext_vector_type(8))) __bf16 bf16x8;
typedef __attribute__((ext_vector_type(8))) short short8;
typedef __attribute__((ext_vector_type(4))) float f32x4;

union Cvt8 { __bf16 h[8]; short8 s8; };

__device__ __forceinline__ float fast_tanh(float x) {
  float e = __expf(2.0f * x);
  return 1.0f - __fdividef(2.0f, e + 1.0f);
}

__device__ __forceinline__ void gload_lds16(const void* g, void* l) {
  __builtin_amdgcn_global_load_lds(
      (const __attribute__((address_space(1))) unsigned int*)g,
      (__attribute__((address_space(3))) unsigned int*)l, 16, 0, 0);
}

// ---- K0a: pack W1 (f32 [D][U]) -> bf16 MFMA B-fragment order ----
// W1f[ks][ct][lane][j]: k = ks*32 + (lane>>4)*8 + j, u = ct*16 + (lane&15)
__global__ void pack_w1_kernel(const float* __restrict__ W1, __bf16* __restrict__ W1f) {
  int idx = blockIdx.x * 256 + threadIdx.x;   // [16 ks][32 ct][64 lane]
  int l  = idx & 63;
  int ct = (idx >> 6) & 31;
  int ks = idx >> 11;
  int col   = ct * 16 + (l & 15);
  int kbase = ks * 32 + (l >> 4) * 8;
  Cvt8 u;
#pragma unroll
  for (int j = 0; j < 8; ++j) u.h[j] = (__bf16)W1[(size_t)(kbase + j) * NU + col];
  *reinterpret_cast<short8*>(W1f + (size_t)idx * 8) = u.s8;
}

// ---- K0b: pq[b][u] = query[b]@W2[:,u] + b2[u] + b1[u] ----
__global__ void proj_query_kernel(const float* __restrict__ query, const float* __restrict__ W2,
                                  const float* __restrict__ b2, const float* __restrict__ b1,
                                  float* __restrict__ pq) {
  int b = blockIdx.y;
  int u = blockIdx.x * 256 + threadIdx.x;
  const float* q = query + (size_t)b * ND;
  float acc = b2[u] + b1[u];
  for (int k = 0; k < ND; ++k) acc += q[k] * W2[(size_t)k * NU + u];
  pq[(size_t)b * NU + u] = acc;
}

// ---- K2: score[b][s] = sum_u tanh(values[b,s,:]@W1[:,u] + pq[b][u]) * V[u] ----
// 64-row tile, 8 waves; wave w covers cols nb*256 + w*32 .. +32 per nb pass.
// values in fragment-linear LDS (R5 layout); W1f kg-slices through the ring.
__global__ __launch_bounds__(512, 2)
void score_kernel(const float* __restrict__ values, const __bf16* __restrict__ W1f,
                  const float* __restrict__ pq, const float* __restrict__ V,
                  float* __restrict__ scoreW) {
  __shared__ __align__(16) char ldsb[133120]; // 64KB values + 4x16KB ring + 2KB sbuf
  char* vtile = ldsb;
  char* bring = ldsb + 65536;
  float* sbuf = (float*)(ldsb + 131072);      // [8 waves][64 rows]

  int bid = blockIdx.x;                       // 2048 = 32 b * 64 tiles
  int b = bid >> 6;
  int s0 = (bid & 63) * 64;
  int tid = threadIdx.x;                      // 512
  int l = tid & 63;
  int w = tid >> 6;
  int lane_col = l & 15;
  int lane_k8  = l >> 4;

  float pqv[4], Vv[4];
#pragma unroll
  for (int nb = 0; nb < 2; ++nb)
#pragma unroll
    for (int cf = 0; cf < 2; ++cf) {
      int col = nb * 256 + w * 32 + cf * 16 + lane_col;
      pqv[nb * 2 + cf] = pq[(size_t)b * NU + col];
      Vv[nb * 2 + cf]  = V[col];
    }

  // stage B slice j (16 ct x 1KB = 16KB) into ring slot j&3: 2 gload_lds/thread
  const char* wbase = (const char*)W1f;
  auto stageB = [&](int j) {
    int nb = j >> 4, ks = j & 15;
    const char* src = wbase + ((size_t)(ks * 32 + nb * 16) << 10);
    char* dst = bring + (j & 3) * 16384;
    gload_lds16(src + tid * 16, dst + tid * 16);
    gload_lds16(src + 8192 + tid * 16, dst + 8192 + tid * 16);
  };

  // ---- prologue: issue B slices 0..2, then stage values tile (fp32->bf16) ----
  stageB(0); stageB(1); stageB(2);
  const float* vbase = values + ((size_t)b * NS + s0) * ND;
#pragma unroll
  for (int i = 0; i < 8; ++i) {
    int c  = i * 512 + tid;                   // fragment-linear chunk id
    int t  = c >> 10;
    int kg = (c >> 6) & 15;
    int ln = c & 63;
    int s  = t * 16 + (ln & 15);
    int c8 = kg * 4 + (ln >> 4);
    const f32x4* p = reinterpret_cast<const f32x4*>(vbase + (size_t)s * ND + c8 * 8);
    f32x4 f0 = p[0], f1 = p[1];
    Cvt8 u;
    u.h[0] = (__bf16)f0.x; u.h[1] = (__bf16)f0.y; u.h[2] = (__bf16)f0.z; u.h[3] = (__bf16)f0.w;
    u.h[4] = (__bf16)f1.x; u.h[5] = (__bf16)f1.y; u.h[6] = (__bf16)f1.z; u.h[7] = (__bf16)f1.w;
    *reinterpret_cast<short8*>(vtile + (size_t)c * 16) = u.s8;
  }
  __syncthreads();                            // one-time full drain: slots 0-2 + values ready

  float partial[4][4];
#pragma unroll
  for (int t = 0; t < 4; ++t)
#pragma unroll
    for (int r = 0; r < 4; ++r) partial[t][r] = 0.f;

#pragma unroll
  for (int nb = 0; nb < 2; ++nb) {
    f32x4 acc[4][2];
#pragma unroll
    for (int t = 0; t < 4; ++t)
#pragma unroll
      for (int cf = 0; cf < 2; ++cf) acc[t][cf] = (f32x4){0.f, 0.f, 0.f, 0.f};

#pragma unroll
    for (int ks = 0; ks < 16; ++ks) {
      const int kg = nb * 16 + ks;
      // counted wait: own stage-kg loads landed (stages kg+1,kg+2 = 4 may fly)
      asm volatile("s_waitcnt vmcnt(4)" ::: "memory");
      __builtin_amdgcn_s_barrier();           // all waves' stage-kg landed; reads of kg-1 done
      char* slot = bring + (kg & 3) * 16384;
      bf16x8 a[4], bb[2];
#pragma unroll
      for (int t = 0; t < 4; ++t)
        a[t] = *reinterpret_cast<const bf16x8*>(vtile + (((t * 16 + ks) * 64 + l) << 4));
#pragma unroll
      for (int cf = 0; cf < 2; ++cf)
        bb[cf] = *reinterpret_cast<const bf16x8*>(slot + ((w * 2 + cf) << 10) + (l << 4));
#pragma unroll
      for (int cf = 0; cf < 2; ++cf)
#pragma unroll
        for (int t = 0; t < 4; ++t)
          acc[t][cf] = __builtin_amdgcn_mfma_f32_16x16x32_bf16(a[t], bb[cf], acc[t][cf], 0, 0, 0);
      if (kg + 3 < 32) stageB(kg + 3);        // refill slot (kg-1)&3: safe post-barrier
    }

    // fold this nb's cols: tanh(proj + pq) * V
#pragma unroll
    for (int cf = 0; cf < 2; ++cf)
#pragma unroll
      for (int t = 0; t < 4; ++t)
#pragma unroll
        for (int r = 0; r < 4; ++r)
          partial[t][r] += fast_tanh(acc[t][cf][r] + pqv[nb * 2 + cf]) * Vv[nb * 2 + cf];
  }

  // reduce over 16 lane_col lanes, then across waves via LDS
#pragma unroll
  for (int off = 1; off < 16; off <<= 1)
#pragma unroll
    for (int t = 0; t < 4; ++t)
#pragma unroll
      for (int r = 0; r < 4; ++r) partial[t][r] += __shfl_xor(partial[t][r], off);

  if (lane_col == 0) {
#pragma unroll
    for (int t = 0; t < 4; ++t)
#pragma unroll
      for (int r = 0; r < 4; ++r)
        sbuf[w * 64 + t * 16 + lane_k8 * 4 + r] = partial[t][r];
  }
  __syncthreads();
  if (tid < 64) {
    float sc = 0.f;
#pragma unroll
    for (int wv = 0; wv < 8; ++wv) sc += sbuf[wv * 64 + tid];
    scoreW[(size_t)b * NS + s0 + tid] = sc;   // bv omitted: softmax shift-invariant
  }
}

// ---- K3: softmax over S per batch -> attention weights (d_out tail) ----
__global__ void softmax_kernel(const float* __restrict__ scoreW, float* __restrict__ attn) {
  int b = blockIdx.x, tid = threadIdx.x;      // 256 threads
  __shared__ float sred[8];
  const float* sc = scoreW + (size_t)b * NS;
  float m = -3.0e38f;
  for (int s = tid; s < NS; s += 256) m = fmaxf(m, sc[s]);
#pragma unroll
  for (int off = 1; off < 64; off <<= 1) m = fmaxf(m, __shfl_xor(m, off));
  if ((tid & 63) == 0) sred[tid >> 6] = m;
  __syncthreads();
  m = fmaxf(fmaxf(sred[0], sred[1]), fmaxf(sred[2], sred[3]));
  float sum = 0.f;
  for (int s = tid; s < NS; s += 256) sum += __expf(sc[s] - m);
#pragma unroll
  for (int off = 1; off < 64; off <<= 1) sum += __shfl_xor(sum, off);
  if ((tid & 63) == 0) sred[4 + (tid >> 6)] = sum;
  __syncthreads();
  float inv = 1.f / (sred[4] + sred[5] + sred[6] + sred[7]);
  float* ab = attn + (size_t)b * NS;
  for (int s = tid; s < NS; s += 256) ab[s] = __expf(sc[s] - m) * inv;
}

// ---- K4: context partials over 256-row chunks ----
__global__ void context_partial_kernel(const float* __restrict__ values,
                                       const float* __restrict__ attn,
                                       float* __restrict__ ctxpart) {
  int blk = blockIdx.x;                       // 32 b * 16 chunks
  int b = blk >> 4, c = blk & 15;
  int tid = threadIdx.x;                      // 256
  int t2 = tid & 127;
  int sg = tid >> 7;
  const float* vb = values + ((size_t)b * NS + c * 256) * ND;
  const float* ab = attn + (size_t)b * NS + c * 256;
  f32x4 acc = {0.f, 0.f, 0.f, 0.f};
  for (int s = sg; s < 256; s += 2) {
    float wv = ab[s];
    f32x4 v = *reinterpret_cast<const f32x4*>(vb + (size_t)s * ND + t2 * 4);
    acc += v * wv;
  }
  __shared__ f32x4 red[128];
  if (sg == 1) red[t2] = acc;
  __syncthreads();
  if (sg == 0) {
    acc += red[t2];
    *reinterpret_cast<f32x4*>(ctxpart + (size_t)blk * ND + t2 * 4) = acc;
  }
}

// ---- K5: reduce chunk partials -> context_vector (d_out head) ----
__global__ void context_reduce_kernel(const float* __restrict__ ctxpart, float* __restrict__ ctx) {
  int b = blockIdx.x, tid = threadIdx.x;      // 128 threads * float4
  f32x4 acc = {0.f, 0.f, 0.f, 0.f};
  for (int c = 0; c < 16; ++c)
    acc += *reinterpret_cast<const f32x4*>(ctxpart + (size_t)(b * 16 + c) * ND + tid * 4);
  *reinterpret_cast<f32x4*>(ctx + (size_t)b * ND + tid * 4) = acc;
}

extern "C" void kernel_launch(void* const* d_in, const int* in_sizes, int n_in,
                              void* d_out, int out_size, void* d_ws, size_t ws_size,
                              hipStream_t stream) {
  const float* query  = (const float*)d_in[0];
  const float* values = (const float*)d_in[1];
  const float* W1     = (const float*)d_in[2];
  const float* b1     = (const float*)d_in[3];
  const float* W2     = (const float*)d_in[4];
  const float* b2     = (const float*)d_in[5];
  const float* V      = (const float*)d_in[6];
  // d_in[7] = bv: softmax-invariant, score not an output: dropped.

  float* ctx_out  = (float*)d_out;            // [32][512]
  float* attn_out = ctx_out + NB * ND;        // [32][4096]

  char* ws = (char*)d_ws;
  __bf16* W1f    = (__bf16*)ws;               // 512 KB
  float*  pq     = (float*)(ws + 524288);     // 64 KB
  float*  scoreW = (float*)(ws + 589824);     // 512 KB
  float*  ctxp   = (float*)(ws + 1114112);    // 1 MB

  hipLaunchKernelGGL(pack_w1_kernel,        dim3(128),     dim3(256), 0, stream, W1, W1f);
  hipLaunchKernelGGL(proj_query_kernel,     dim3(2, NB),   dim3(256), 0, stream, query, W2, b2, b1, pq);
  hipLaunchKernelGGL(score_kernel,          dim3(2048),    dim3(512), 0, stream, values, W1f, pq, V, scoreW);
  hipLaunchKernelGGL(softmax_kernel,        dim3(NB),      dim3(256), 0, stream, scoreW, attn_out);
  hipLaunchKernelGGL(context_partial_kernel,dim3(NB * 16), dim3(256), 0, stream, values, attn_out, ctxp);
  hipLaunchKernelGGL(context_reduce_kernel, dim3(NB),      dim3(128), 0, stream, ctxp, ctx_out);
}